// Round 4
// baseline (2042.382 us; speedup 1.0000x reference)
//
#include <hip/hip_runtime.h>
#include <cmath>
#include <stdint.h>

#define NLEV  16
#define TSIZE (1u<<19)
#define PRES  512
#define PFD   8
#define HID   64

struct ResArr { float v[NLEV]; };

__device__ __forceinline__ float4 ld4(const float* p){ return *reinterpret_cast<const float4*>(p); }

// acc[o] += wT_col[o] * v  for o=0..63, static indexing only (keeps acc in VGPRs)
#define AXPY64(A, WPTR, V) do { const float* _w=(WPTR); const float _v=(V); \
  _Pragma("unroll") \
  for (int _o=0;_o<64;_o+=4){ float4 _w4=ld4(_w+_o); \
    A[_o+0]=fmaf(_w4.x,_v,A[_o+0]); A[_o+1]=fmaf(_w4.y,_v,A[_o+1]); \
    A[_o+2]=fmaf(_w4.z,_v,A[_o+2]); A[_o+3]=fmaf(_w4.w,_v,A[_o+3]); } } while(0)

// 32-wide variant for the register-pressure-split color1
#define AXPY32(A, WPTR, V) do { const float* _w=(WPTR); const float _v=(V); \
  _Pragma("unroll") \
  for (int _o=0;_o<32;_o+=4){ float4 _w4=ld4(_w+_o); \
    A[_o+0]=fmaf(_w4.x,_v,A[_o+0]); A[_o+1]=fmaf(_w4.y,_v,A[_o+1]); \
    A[_o+2]=fmaf(_w4.z,_v,A[_o+2]); A[_o+3]=fmaf(_w4.w,_v,A[_o+3]); } } while(0)

__device__ __forceinline__ void plane_enc(const float* __restrict__ planes,
                                          float p0, float p1, float p2, float* pfv)
{
#pragma unroll
    for (int i=0;i<3;i++){
        float ua = (i==2? p1 : p0)*511.f;
        float va = (i==0? p1 : p2)*511.f;
        float uf=floorf(ua), vf=floorf(va);
        float wu=ua-uf, wv=va-vf;
        int u0=(int)uf; u0 = u0<0?0:(u0>510?510:u0);
        int v0=(int)vf; v0 = v0<0?0:(v0>510?510:v0);
        const float* pl = planes + ((size_t)i*PRES*PRES + (size_t)(u0*PRES+v0))*PFD;
        float4 a0=ld4(pl),              a1=ld4(pl+4);
        float4 b0=ld4(pl+PFD),          b1=ld4(pl+PFD+4);
        float4 c0=ld4(pl+PRES*PFD),     c1=ld4(pl+PRES*PFD+4);
        float4 d0=ld4(pl+PRES*PFD+PFD), d1=ld4(pl+PRES*PFD+PFD+4);
        float w00=(1.f-wu)*(1.f-wv), w01=(1.f-wu)*wv, w10=wu*(1.f-wv), w11=wu*wv;
        pfv[i*8+0]=a0.x*w00+b0.x*w01+c0.x*w10+d0.x*w11;
        pfv[i*8+1]=a0.y*w00+b0.y*w01+c0.y*w10+d0.y*w11;
        pfv[i*8+2]=a0.z*w00+b0.z*w01+c0.z*w10+d0.z*w11;
        pfv[i*8+3]=a0.w*w00+b0.w*w01+c0.w*w10+d0.w*w11;
        pfv[i*8+4]=a1.x*w00+b1.x*w01+c1.x*w10+d1.x*w11;
        pfv[i*8+5]=a1.y*w00+b1.y*w01+c1.y*w10+d1.y*w11;
        pfv[i*8+6]=a1.z*w00+b1.z*w01+c1.z*w10+d1.z*w11;
        pfv[i*8+7]=a1.w*w00+b1.w*w01+c1.w*w10+d1.w*w11;
    }
}

// ===================== K1: hash + plane encode + sigma MLP =====================
// Empirical toolchain law: __launch_bounds__(256,N) -> VGPR cap 256/N.
// (256,2) -> 128-VGPR cap; peak live ~110 (acc[64]+gather temps) -> no spill.
// LDS 18.4KB; occupancy VGPR-limited at 16 waves/CU (50%).
__global__ __launch_bounds__(256, 2)
void nerf_k1(const float* __restrict__ x,
             const float* __restrict__ hash_tables,
             const float* __restrict__ planes,
             const float* __restrict__ w_sigma0,
             const float* __restrict__ w_sigma1,
             float* __restrict__ ws16,
             ResArr res, int npts)
{
    __shared__ float s_ws0T[56*64];   // sigma0: in 56 -> out 64 (transposed)
    __shared__ float s_ws1T[64*16];   // sigma1: in 64 -> out 16 (transposed)

    for (int i = threadIdx.x; i < 56*64;  i += 256){ int k=i>>6, o=i&63; s_ws0T[i] = w_sigma0[o*56+k]; }
    for (int i = threadIdx.x; i < 64*16;  i += 256){ int k=i>>4, j=i&15; s_ws1T[i] = w_sigma1[j*64+k]; }
    __syncthreads();

    int n = blockIdx.x*256 + threadIdx.x;
    if (n >= npts) return;

    const float* xr = x + (size_t)n*7;
    float px=xr[0], py=xr[1], pz=xr[2];
    float p0=(px+1.f)*0.5f, p1=(py+1.f)*0.5f, p2=(pz+1.f)*0.5f;

    float acc[HID];
#pragma unroll
    for (int o=0;o<HID;o++) acc[o]=0.f;

    const float2* tabs = reinterpret_cast<const float2*>(hash_tables);
    for (int l=0; l<NLEV; l++){
        float R = res.v[l];
        float ax=p0*R, ay=p1*R, az=p2*R;
        float fx=floorf(ax), fy=floorf(ay), fz=floorf(az);
        float rx=ax-fx, ry=ay-fy, rz=az-fz;
        uint32_t ix=(uint32_t)fx, iy=(uint32_t)fy, iz=(uint32_t)fz;
        const float2* tab = tabs + (size_t)l*TSIZE;
        uint32_t hx0=ix,               hx1=ix+1u;
        uint32_t hy0=iy*2654435761u,   hy1=(iy+1u)*2654435761u;
        uint32_t hz0=iz*805459861u,    hz1=(iz+1u)*805459861u;
        float wx0=1.f-rx, wx1=rx, wy0=1.f-ry, wy1=ry, wz0=1.f-rz, wz1=rz;
        float f0=0.f, f1=0.f;
#pragma unroll
        for (int c=0;c<8;c++){
            uint32_t hxx=(c&4)?hx1:hx0;
            uint32_t hyy=(c&2)?hy1:hy0;
            uint32_t hzz=(c&1)?hz1:hz0;
            uint32_t idx=(hxx^hyy^hzz)&(TSIZE-1u);
            float2 t = tab[idx];
            float w = ((c&4)?wx1:wx0)*((c&2)?wy1:wy0)*((c&1)?wz1:wz0);
            f0 = fmaf(w,t.x,f0);
            f1 = fmaf(w,t.y,f1);
        }
        AXPY64(acc, &s_ws0T[(2*l+0)*64], f0);
        AXPY64(acc, &s_ws0T[(2*l+1)*64], f1);
    }

    float pfv[24];
    plane_enc(planes, p0, p1, p2, pfv);
#pragma unroll
    for (int j=0;j<24;j++){
        AXPY64(acc, &s_ws0T[(32+j)*64], pfv[j]);
    }

    // sigma1: 16 outputs from relu(acc)
    float h1[16];
#pragma unroll
    for (int j=0;j<16;j++) h1[j]=0.f;
#pragma unroll
    for (int k=0;k<HID;k++){
        float v = fmaxf(acc[k], 0.f);
        const float* wr = &s_ws1T[k*16];
#pragma unroll
        for (int j=0;j<16;j+=4){
            float4 w=ld4(wr+j);
            h1[j+0]=fmaf(w.x,v,h1[j+0]); h1[j+1]=fmaf(w.y,v,h1[j+1]);
            h1[j+2]=fmaf(w.z,v,h1[j+2]); h1[j+3]=fmaf(w.w,v,h1[j+3]);
        }
    }
    float sg = fminf(fmaxf(h1[0], -15.f), 15.f);
    float sigma = expf(sg);

    // ws layout per point: [geo(15), sigma(1)]
    float* w = ws16 + (size_t)n*16;
    *reinterpret_cast<float4*>(w+0)  = make_float4(h1[1],h1[2],h1[3],h1[4]);
    *reinterpret_cast<float4*>(w+4)  = make_float4(h1[5],h1[6],h1[7],h1[8]);
    *reinterpret_cast<float4*>(w+8)  = make_float4(h1[9],h1[10],h1[11],h1[12]);
    *reinterpret_cast<float4*>(w+12) = make_float4(h1[13],h1[14],h1[15],sigma);
}

// ===================== K2: SH + color MLP =====================
// (256,2) -> 128-VGPR cap. color1 split into 2x32-output passes: peak live ~106.
// LDS 43.8KB -> 3 blocks/CU (37.5% occ) — enough for a VALU-bound phase.
__global__ __launch_bounds__(256, 2)
void nerf_k2(const float* __restrict__ x,
             const float* __restrict__ planes,
             const float* __restrict__ embed_a,
             const float* __restrict__ w_color0,
             const float* __restrict__ w_color1,
             const float* __restrict__ w_color2,
             const float* __restrict__ ws16,
             float* __restrict__ out, int npts)
{
    __shared__ float s_wc0T[103*64];  // color0: in 103 -> out 64
    __shared__ float s_wc1T[64*64];   // color1: in 64 -> out 64
    __shared__ float s_wc2T[64*4];    // color2: in 64 -> out 3 (pad 4)

    for (int i = threadIdx.x; i < 103*64; i += 256){ int k=i>>6, o=i&63; s_wc0T[i] = w_color0[o*103+k]; }
    for (int i = threadIdx.x; i < 64*64;  i += 256){ int k=i>>6, o=i&63; s_wc1T[i] = w_color1[o*64+k]; }
    for (int i = threadIdx.x; i < 64*4;   i += 256){ int k=i>>2, o=i&3;  s_wc2T[i] = (o<3)? w_color2[o*64+k] : 0.f; }
    __syncthreads();

    int n = blockIdx.x*256 + threadIdx.x;
    if (n >= npts) return;

    const float* xr = x + (size_t)n*7;
    float dx=xr[3], dy=xr[4], dz=xr[5];
    float appf = xr[6];
    float p0=(xr[0]+1.f)*0.5f, p1=(xr[1]+1.f)*0.5f, p2=(xr[2]+1.f)*0.5f;

    float acc[HID];
#pragma unroll
    for (int o=0;o<HID;o++) acc[o]=0.f;

    // SH(16)
    {
        float nrm = sqrtf(dx*dx+dy*dy+dz*dz);
        float sx=dx/nrm, sy=dy/nrm, sz=dz/nrm;
        float xx=sx*sx, yy=sy*sy, zz=sz*sz, xyv=sx*sy, yzv=sy*sz, xzv=sx*sz;
        float sh[16];
        sh[0]=0.28209479177387814f;
        sh[1]=-0.48860251190291987f*sy;
        sh[2]= 0.48860251190291987f*sz;
        sh[3]=-0.48860251190291987f*sx;
        sh[4]= 1.0925484305920792f*xyv;
        sh[5]=-1.0925484305920792f*yzv;
        sh[6]= 0.94617469575756f*zz-0.31539156525252005f;
        sh[7]=-1.0925484305920792f*xzv;
        sh[8]= 0.5462742152960396f*(xx-yy);
        sh[9]=-0.5900435899266435f*sy*(3.f*xx-yy);
        sh[10]=2.890611442640554f*xyv*sz;
        sh[11]=-0.4570457994644658f*sy*(4.f*zz-xx-yy);
        sh[12]=0.3731763325901154f*sz*(2.f*zz-3.f*xx-3.f*yy);
        sh[13]=-0.4570457994644658f*sx*(4.f*zz-xx-yy);
        sh[14]=1.445305721320277f*sz*(xx-yy);
        sh[15]=-0.5900435899266435f*sx*(xx-3.f*yy);
#pragma unroll
        for (int k=0;k<16;k++){
            AXPY64(acc, &s_wc0T[k*64], sh[k]);
        }
    }

    // geo(15) + sigma from workspace
    float sigma;
    {
        const float* wsr = ws16 + (size_t)n*16;
        float4 g0=ld4(wsr), g1=ld4(wsr+4), g2=ld4(wsr+8), g3=ld4(wsr+12);
        float geo[15] = {g0.x,g0.y,g0.z,g0.w, g1.x,g1.y,g1.z,g1.w,
                         g2.x,g2.y,g2.z,g2.w, g3.x,g3.y,g3.z};
        sigma = g3.w;
#pragma unroll
        for (int j=0;j<15;j++){
            AXPY64(acc, &s_wc0T[(16+j)*64], geo[j]);
        }
    }

    // app(48)
    {
        int ai = (int)appf;
        const float* ar = embed_a + (size_t)ai*48;
        for (int q=0;q<12;q++){
            float4 av = ld4(ar + q*4);
            const float* wc = &s_wc0T[(31+q*4)*64];
            AXPY64(acc, wc,       av.x);
            AXPY64(acc, wc+64,    av.y);
            AXPY64(acc, wc+128,   av.z);
            AXPY64(acc, wc+192,   av.w);
        }
    }

    // pf(24), recomputed (cheap, avoids storing 24 floats/pt)
    {
        float pfv[24];
        plane_enc(planes, p0, p1, p2, pfv);
#pragma unroll
        for (int j=0;j<24;j++){
            AXPY64(acc, &s_wc0T[(79+j)*64], pfv[j]);
        }
    }

    // relu color0 output in place
#pragma unroll
    for (int k=0;k<HID;k++) acc[k] = fmaxf(acc[k], 0.f);

    // color1 + color2, split into two 32-output passes to cap live registers.
    float c0a=0.f, c1a=0.f, c2a=0.f;
    {
        float acc2h[32];
#pragma unroll
        for (int o=0;o<32;o++) acc2h[o]=0.f;
#pragma unroll
        for (int k=0;k<HID;k++){
            AXPY32(acc2h, &s_wc1T[k*64], acc[k]);
        }
#pragma unroll
        for (int o=0;o<32;o++){
            float v = fmaxf(acc2h[o], 0.f);
            float4 w = ld4(&s_wc2T[o*4]);
            c0a=fmaf(w.x,v,c0a); c1a=fmaf(w.y,v,c1a); c2a=fmaf(w.z,v,c2a);
        }
    }
    {
        float acc2h[32];
#pragma unroll
        for (int o=0;o<32;o++) acc2h[o]=0.f;
#pragma unroll
        for (int k=0;k<HID;k++){
            AXPY32(acc2h, &s_wc1T[k*64+32], acc[k]);
        }
#pragma unroll
        for (int o=0;o<32;o++){
            float v = fmaxf(acc2h[o], 0.f);
            float4 w = ld4(&s_wc2T[(32+o)*4]);
            c0a=fmaf(w.x,v,c0a); c1a=fmaf(w.y,v,c1a); c2a=fmaf(w.z,v,c2a);
        }
    }

    float4 o4;
    o4.x = 1.f/(1.f+expf(-c0a));
    o4.y = 1.f/(1.f+expf(-c1a));
    o4.z = 1.f/(1.f+expf(-c2a));
    o4.w = sigma;
    *reinterpret_cast<float4*>(out + (size_t)n*4) = o4;
}

// ===================== fallback single kernel (used only if ws too small) =====================
__global__ __launch_bounds__(256, 1)
void nerf_fwd(const float* __restrict__ x,
              const float* __restrict__ hash_tables,
              const float* __restrict__ planes,
              const float* __restrict__ embed_a,
              const float* __restrict__ w_sigma0,
              const float* __restrict__ w_sigma1,
              const float* __restrict__ w_color0,
              const float* __restrict__ w_color1,
              const float* __restrict__ w_color2,
              float* __restrict__ out,
              ResArr res, int npts)
{
    __shared__ float s_ws0T[56*64];
    __shared__ float s_ws1T[64*16];
    __shared__ float s_wc0T[103*64];
    __shared__ float s_wc1T[64*64];
    __shared__ float s_wc2T[64*4];

    for (int i = threadIdx.x; i < 56*64;  i += 256){ int k=i>>6, o=i&63; s_ws0T[i] = w_sigma0[o*56+k]; }
    for (int i = threadIdx.x; i < 64*16;  i += 256){ int k=i>>4, j=i&15; s_ws1T[i] = w_sigma1[j*64+k]; }
    for (int i = threadIdx.x; i < 103*64; i += 256){ int k=i>>6, o=i&63; s_wc0T[i] = w_color0[o*103+k]; }
    for (int i = threadIdx.x; i < 64*64;  i += 256){ int k=i>>6, o=i&63; s_wc1T[i] = w_color1[o*64+k]; }
    for (int i = threadIdx.x; i < 64*4;   i += 256){ int k=i>>2, o=i&3;  s_wc2T[i] = (o<3)? w_color2[o*64+k] : 0.f; }
    __syncthreads();

    int n = blockIdx.x*256 + threadIdx.x;
    if (n >= npts) return;

    const float* xr = x + (size_t)n*7;
    float px=xr[0], py=xr[1], pz=xr[2];
    float dx=xr[3], dy=xr[4], dz=xr[5];
    float appf = xr[6];
    float p0=(px+1.f)*0.5f, p1=(py+1.f)*0.5f, p2=(pz+1.f)*0.5f;

    float acc[HID];
#pragma unroll
    for (int o=0;o<HID;o++) acc[o]=0.f;

    const float2* tabs = reinterpret_cast<const float2*>(hash_tables);
    for (int l=0; l<NLEV; l++){
        float R = res.v[l];
        float ax=p0*R, ay=p1*R, az=p2*R;
        float fx=floorf(ax), fy=floorf(ay), fz=floorf(az);
        float rx=ax-fx, ry=ay-fy, rz=az-fz;
        uint32_t ix=(uint32_t)fx, iy=(uint32_t)fy, iz=(uint32_t)fz;
        const float2* tab = tabs + (size_t)l*TSIZE;
        uint32_t hx0=ix,               hx1=ix+1u;
        uint32_t hy0=iy*2654435761u,   hy1=(iy+1u)*2654435761u;
        uint32_t hz0=iz*805459861u,    hz1=(iz+1u)*805459861u;
        float wx0=1.f-rx, wx1=rx, wy0=1.f-ry, wy1=ry, wz0=1.f-rz, wz1=rz;
        float f0=0.f, f1=0.f;
#pragma unroll
        for (int c=0;c<8;c++){
            uint32_t hxx=(c&4)?hx1:hx0;
            uint32_t hyy=(c&2)?hy1:hy0;
            uint32_t hzz=(c&1)?hz1:hz0;
            uint32_t idx=(hxx^hyy^hzz)&(TSIZE-1u);
            float2 t = tab[idx];
            float w = ((c&4)?wx1:wx0)*((c&2)?wy1:wy0)*((c&1)?wz1:wz0);
            f0 = fmaf(w,t.x,f0);
            f1 = fmaf(w,t.y,f1);
        }
        AXPY64(acc, &s_ws0T[(2*l+0)*64], f0);
        AXPY64(acc, &s_ws0T[(2*l+1)*64], f1);
    }

    float pfv[24];
    plane_enc(planes, p0, p1, p2, pfv);
#pragma unroll
    for (int j=0;j<24;j++){
        AXPY64(acc, &s_ws0T[(32+j)*64], pfv[j]);
    }

    float h1[16];
#pragma unroll
    for (int j=0;j<16;j++) h1[j]=0.f;
#pragma unroll
    for (int k=0;k<HID;k++){
        float v = fmaxf(acc[k], 0.f);
        const float* wr = &s_ws1T[k*16];
#pragma unroll
        for (int j=0;j<16;j+=4){
            float4 w=ld4(wr+j);
            h1[j+0]=fmaf(w.x,v,h1[j+0]); h1[j+1]=fmaf(w.y,v,h1[j+1]);
            h1[j+2]=fmaf(w.z,v,h1[j+2]); h1[j+3]=fmaf(w.w,v,h1[j+3]);
        }
    }
    float sg = fminf(fmaxf(h1[0], -15.f), 15.f);
    float sigma = expf(sg);

#pragma unroll
    for (int o=0;o<HID;o++) acc[o]=0.f;

    float nrm = sqrtf(dx*dx+dy*dy+dz*dz);
    float sx=dx/nrm, sy=dy/nrm, sz=dz/nrm;
    float xx=sx*sx, yy=sy*sy, zz=sz*sz, xyv=sx*sy, yzv=sy*sz, xzv=sx*sz;
    float sh[16];
    sh[0]=0.28209479177387814f;
    sh[1]=-0.48860251190291987f*sy;
    sh[2]= 0.48860251190291987f*sz;
    sh[3]=-0.48860251190291987f*sx;
    sh[4]= 1.0925484305920792f*xyv;
    sh[5]=-1.0925484305920792f*yzv;
    sh[6]= 0.94617469575756f*zz-0.31539156525252005f;
    sh[7]=-1.0925484305920792f*xzv;
    sh[8]= 0.5462742152960396f*(xx-yy);
    sh[9]=-0.5900435899266435f*sy*(3.f*xx-yy);
    sh[10]=2.890611442640554f*xyv*sz;
    sh[11]=-0.4570457994644658f*sy*(4.f*zz-xx-yy);
    sh[12]=0.3731763325901154f*sz*(2.f*zz-3.f*xx-3.f*yy);
    sh[13]=-0.4570457994644658f*sx*(4.f*zz-xx-yy);
    sh[14]=1.445305721320277f*sz*(xx-yy);
    sh[15]=-0.5900435899266435f*sx*(xx-3.f*yy);
#pragma unroll
    for (int k=0;k<16;k++){
        AXPY64(acc, &s_wc0T[k*64], sh[k]);
    }
#pragma unroll
    for (int j=0;j<15;j++){
        AXPY64(acc, &s_wc0T[(16+j)*64], h1[1+j]);
    }
    {
        int ai = (int)appf;
        const float* ar = embed_a + (size_t)ai*48;
        for (int q=0;q<12;q++){
            float4 av = ld4(ar + q*4);
            const float* wc = &s_wc0T[(31+q*4)*64];
            AXPY64(acc, wc,       av.x);
            AXPY64(acc, wc+64,    av.y);
            AXPY64(acc, wc+128,   av.z);
            AXPY64(acc, wc+192,   av.w);
        }
    }
#pragma unroll
    for (int j=0;j<24;j++){
        AXPY64(acc, &s_wc0T[(79+j)*64], pfv[j]);
    }

    float acc2[HID];
#pragma unroll
    for (int o=0;o<HID;o++) acc2[o]=0.f;
#pragma unroll
    for (int k=0;k<HID;k++){
        float v = fmaxf(acc[k], 0.f);
        AXPY64(acc2, &s_wc1T[k*64], v);
    }

    float c0a=0.f, c1a=0.f, c2a=0.f;
#pragma unroll
    for (int k=0;k<HID;k++){
        float v = fmaxf(acc2[k], 0.f);
        float4 w = ld4(&s_wc2T[k*4]);
        c0a=fmaf(w.x,v,c0a); c1a=fmaf(w.y,v,c1a); c2a=fmaf(w.z,v,c2a);
    }
    float4 o4;
    o4.x = 1.f/(1.f+expf(-c0a));
    o4.y = 1.f/(1.f+expf(-c1a));
    o4.z = 1.f/(1.f+expf(-c2a));
    o4.w = sigma;
    *reinterpret_cast<float4*>(out + (size_t)n*4) = o4;
}

extern "C" void kernel_launch(void* const* d_in, const int* in_sizes, int n_in,
                              void* d_out, int out_size, void* d_ws, size_t ws_size,
                              hipStream_t stream) {
    const float* x        = (const float*)d_in[0];
    const float* ht       = (const float*)d_in[1];
    const float* planes   = (const float*)d_in[2];
    const float* embed_a  = (const float*)d_in[3];
    const float* w_sigma0 = (const float*)d_in[4];
    const float* w_sigma1 = (const float*)d_in[5];
    const float* w_color0 = (const float*)d_in[6];
    const float* w_color1 = (const float*)d_in[7];
    const float* w_color2 = (const float*)d_in[8];
    float* out = (float*)d_out;

    int npts = in_sizes[0] / 7;

    // Replicate numpy's RES bit-exactly (same libm chain).
    ResArr res;
    double b = exp((log(2048.0) - log(16.0)) / 15.0);
    for (int l=0; l<NLEV; l++)
        res.v[l] = (float)floor(16.0 * pow(b, (double)l));

    size_t ws_needed = (size_t)npts * 16 * sizeof(float);
    if (ws_size >= ws_needed) {
        float* ws16 = (float*)d_ws;
        int g1 = (npts + 255) / 256;
        hipLaunchKernelGGL(nerf_k1, dim3(g1), dim3(256), 0, stream,
                           x, ht, planes, w_sigma0, w_sigma1, ws16, res, npts);
        int g2 = (npts + 255) / 256;
        hipLaunchKernelGGL(nerf_k2, dim3(g2), dim3(256), 0, stream,
                           x, planes, embed_a, w_color0, w_color1, w_color2,
                           ws16, out, npts);
    } else {
        int grid = (npts + 255) / 256;
        hipLaunchKernelGGL(nerf_fwd, dim3(grid), dim3(256), 0, stream,
                           x, ht, planes, embed_a,
                           w_sigma0, w_sigma1, w_color0, w_color1, w_color2,
                           out, res, npts);
    }
}

// Round 5
// 1334.439 us; speedup vs baseline: 1.5305x; 1.5305x over previous
//
#include <hip/hip_runtime.h>
#include <cmath>
#include <stdint.h>

#define NLEV  16
#define TSIZE (1u<<19)
#define PRES  512
#define PFD   8
#define HID   64

struct ResArr { float v[NLEV]; };

__device__ __forceinline__ float4 ld4(const float* p){ return *reinterpret_cast<const float4*>(p); }

__device__ __forceinline__ uint16_t f2bf(float f){
    uint32_t u = __float_as_uint(f);
    uint32_t r = (u + 0x7FFFu + ((u>>16)&1u)) >> 16;
    return (uint16_t)r;
}
__device__ __forceinline__ float bf2f(uint32_t h){ return __uint_as_float(h<<16); }

// acc[o] += wT_col[o] * v  for o=0..63, static indexing only
#define AXPY64(A, WPTR, V) do { const float* _w=(WPTR); const float _v=(V); \
  _Pragma("unroll") \
  for (int _o=0;_o<64;_o+=4){ float4 _w4=ld4(_w+_o); \
    A[_o+0]=fmaf(_w4.x,_v,A[_o+0]); A[_o+1]=fmaf(_w4.y,_v,A[_o+1]); \
    A[_o+2]=fmaf(_w4.z,_v,A[_o+2]); A[_o+3]=fmaf(_w4.w,_v,A[_o+3]); } } while(0)

#define AXPY32(A, WPTR, V) do { const float* _w=(WPTR); const float _v=(V); \
  _Pragma("unroll") \
  for (int _o=0;_o<32;_o+=4){ float4 _w4=ld4(_w+_o); \
    A[_o+0]=fmaf(_w4.x,_v,A[_o+0]); A[_o+1]=fmaf(_w4.y,_v,A[_o+1]); \
    A[_o+2]=fmaf(_w4.z,_v,A[_o+2]); A[_o+3]=fmaf(_w4.w,_v,A[_o+3]); } } while(0)

__device__ __forceinline__ void plane_enc(const float* __restrict__ planes,
                                          float p0, float p1, float p2, float* pfv)
{
#pragma unroll
    for (int i=0;i<3;i++){
        float ua = (i==2? p1 : p0)*511.f;
        float va = (i==0? p1 : p2)*511.f;
        float uf=floorf(ua), vf=floorf(va);
        float wu=ua-uf, wv=va-vf;
        int u0=(int)uf; u0 = u0<0?0:(u0>510?510:u0);
        int v0=(int)vf; v0 = v0<0?0:(v0>510?510:v0);
        const float* pl = planes + ((size_t)i*PRES*PRES + (size_t)(u0*PRES+v0))*PFD;
        float4 a0=ld4(pl),              a1=ld4(pl+4);
        float4 b0=ld4(pl+PFD),          b1=ld4(pl+PFD+4);
        float4 c0=ld4(pl+PRES*PFD),     c1=ld4(pl+PRES*PFD+4);
        float4 d0=ld4(pl+PRES*PFD+PFD), d1=ld4(pl+PRES*PFD+PFD+4);
        float w00=(1.f-wu)*(1.f-wv), w01=(1.f-wu)*wv, w10=wu*(1.f-wv), w11=wu*wv;
        pfv[i*8+0]=a0.x*w00+b0.x*w01+c0.x*w10+d0.x*w11;
        pfv[i*8+1]=a0.y*w00+b0.y*w01+c0.y*w10+d0.y*w11;
        pfv[i*8+2]=a0.z*w00+b0.z*w01+c0.z*w10+d0.z*w11;
        pfv[i*8+3]=a0.w*w00+b0.w*w01+c0.w*w10+d0.w*w11;
        pfv[i*8+4]=a1.x*w00+b1.x*w01+c1.x*w10+d1.x*w11;
        pfv[i*8+5]=a1.y*w00+b1.y*w01+c1.y*w10+d1.y*w11;
        pfv[i*8+6]=a1.z*w00+b1.z*w01+c1.z*w10+d1.z*w11;
        pfv[i*8+7]=a1.w*w00+b1.w*w01+c1.w*w10+d1.w*w11;
    }
}

// ===================== K0: level-major hash gather =====================
// grid = 16*chunks, level = bid&15 -> level l pinned to XCD l&7 (round-robin
// dispatch) so each XCD's 4MB L2 holds mostly its own level tables.
// 2 pts/thread -> 16 gathers in flight. Features bf16x2-packed into ws.
__global__ __launch_bounds__(256, 2)
void nerf_k0(const float* __restrict__ x,
             const float* __restrict__ hash_tables,
             uint32_t* __restrict__ feat,
             ResArr res, int npts)
{
    int bid   = blockIdx.x;
    int level = bid & 15;
    int chunk = bid >> 4;
    int n0 = chunk*512 + threadIdx.x;
    int n1 = n0 + 256;
    float R = res.v[level];
    const float2* tab = reinterpret_cast<const float2*>(hash_tables) + (size_t)level*TSIZE;

    bool v0ok = (n0 < npts), v1ok = (n1 < npts);

    float p0a=0,p1a=0,p2a=0, p0b=0,p1b=0,p2b=0;
    if (v0ok){ const float* xr = x + (size_t)n0*7;
        p0a=(xr[0]+1.f)*0.5f; p1a=(xr[1]+1.f)*0.5f; p2a=(xr[2]+1.f)*0.5f; }
    if (v1ok){ const float* xr = x + (size_t)n1*7;
        p0b=(xr[0]+1.f)*0.5f; p1b=(xr[1]+1.f)*0.5f; p2b=(xr[2]+1.f)*0.5f; }

    // point A indices
    float axa=p0a*R, aya=p1a*R, aza=p2a*R;
    float fxa=floorf(axa), fya=floorf(aya), fza=floorf(aza);
    float rxa=axa-fxa, rya=aya-fya, rza=aza-fza;
    uint32_t ixa=(uint32_t)fxa, iya=(uint32_t)fya, iza=(uint32_t)fza;
    uint32_t hx0a=ixa,             hx1a=ixa+1u;
    uint32_t hy0a=iya*2654435761u, hy1a=(iya+1u)*2654435761u;
    uint32_t hz0a=iza*805459861u,  hz1a=(iza+1u)*805459861u;
    // point B indices
    float axb=p0b*R, ayb=p1b*R, azb=p2b*R;
    float fxb=floorf(axb), fyb=floorf(ayb), fzb=floorf(azb);
    float rxb=axb-fxb, ryb=ayb-fyb, rzb=azb-fzb;
    uint32_t ixb=(uint32_t)fxb, iyb=(uint32_t)fyb, izb=(uint32_t)fzb;
    uint32_t hx0b=ixb,             hx1b=ixb+1u;
    uint32_t hy0b=iyb*2654435761u, hy1b=(iyb+1u)*2654435761u;
    uint32_t hz0b=izb*805459861u,  hz1b=(izb+1u)*805459861u;

    float2 ta[8], tb[8];
#pragma unroll
    for (int c=0;c<8;c++){
        uint32_t idx = (((c&4)?hx1a:hx0a) ^ ((c&2)?hy1a:hy0a) ^ ((c&1)?hz1a:hz0a)) & (TSIZE-1u);
        ta[c] = tab[idx];
    }
#pragma unroll
    for (int c=0;c<8;c++){
        uint32_t idx = (((c&4)?hx1b:hx0b) ^ ((c&2)?hy1b:hy0b) ^ ((c&1)?hz1b:hz0b)) & (TSIZE-1u);
        tb[c] = tab[idx];
    }

    float wxa0=1.f-rxa, wya0=1.f-rya, wza0=1.f-rza;
    float f0a=0.f, f1a=0.f;
#pragma unroll
    for (int c=0;c<8;c++){
        float w = ((c&4)?rxa:wxa0)*((c&2)?rya:wya0)*((c&1)?rza:wza0);
        f0a = fmaf(w,ta[c].x,f0a); f1a = fmaf(w,ta[c].y,f1a);
    }
    float wxb0=1.f-rxb, wyb0=1.f-ryb, wzb0=1.f-rzb;
    float f0b=0.f, f1b=0.f;
#pragma unroll
    for (int c=0;c<8;c++){
        float w = ((c&4)?rxb:wxb0)*((c&2)?ryb:wyb0)*((c&1)?rzb:wzb0);
        f0b = fmaf(w,tb[c].x,f0b); f1b = fmaf(w,tb[c].y,f1b);
    }

    size_t base = (size_t)level*npts;
    if (v0ok) feat[base+n0] = (uint32_t)f2bf(f0a) | ((uint32_t)f2bf(f1a)<<16);
    if (v1ok) feat[base+n1] = (uint32_t)f2bf(f0b) | ((uint32_t)f2bf(f1b)<<16);
}

// ===================== K1b: sigma MLP (reads features, overwrites with geo/sigma) =====================
__global__ __launch_bounds__(256, 2)
void nerf_k1b(const float* __restrict__ x,
              const float* __restrict__ planes,
              uint32_t* __restrict__ feat,
              const float* __restrict__ w_sigma0,
              const float* __restrict__ w_sigma1,
              int npts)
{
    __shared__ float s_ws0T[56*64];
    __shared__ float s_ws1T[64*16];
    for (int i = threadIdx.x; i < 56*64;  i += 256){ int k=i>>6, o=i&63; s_ws0T[i] = w_sigma0[o*56+k]; }
    for (int i = threadIdx.x; i < 64*16;  i += 256){ int k=i>>4, j=i&15; s_ws1T[i] = w_sigma1[j*64+k]; }
    __syncthreads();

    int n = blockIdx.x*256 + threadIdx.x;
    if (n >= npts) return;

    uint32_t fl[NLEV];
#pragma unroll
    for (int l=0;l<NLEV;l++) fl[l] = feat[(size_t)l*npts + n];

    float acc[HID];
#pragma unroll
    for (int o=0;o<HID;o++) acc[o]=0.f;

#pragma unroll
    for (int l=0;l<NLEV;l++){
        float f0 = bf2f(fl[l] & 0xFFFFu);
        float f1 = bf2f(fl[l] >> 16);
        AXPY64(acc, &s_ws0T[(2*l+0)*64], f0);
        AXPY64(acc, &s_ws0T[(2*l+1)*64], f1);
    }

    const float* xr = x + (size_t)n*7;
    float p0=(xr[0]+1.f)*0.5f, p1=(xr[1]+1.f)*0.5f, p2=(xr[2]+1.f)*0.5f;
    float pfv[24];
    plane_enc(planes, p0, p1, p2, pfv);
#pragma unroll
    for (int j=0;j<24;j++){
        AXPY64(acc, &s_ws0T[(32+j)*64], pfv[j]);
    }

    float h1[16];
#pragma unroll
    for (int j=0;j<16;j++) h1[j]=0.f;
#pragma unroll
    for (int k=0;k<HID;k++){
        float v = fmaxf(acc[k], 0.f);
        const float* wr = &s_ws1T[k*16];
#pragma unroll
        for (int j=0;j<16;j+=4){
            float4 w=ld4(wr+j);
            h1[j+0]=fmaf(w.x,v,h1[j+0]); h1[j+1]=fmaf(w.y,v,h1[j+1]);
            h1[j+2]=fmaf(w.z,v,h1[j+2]); h1[j+3]=fmaf(w.w,v,h1[j+3]);
        }
    }
    float sg = fminf(fmaxf(h1[0], -15.f), 15.f);
    float sigma = expf(sg);

    // overwrite own feature slots: l=0..14 -> geo, l=15 -> sigma (fp32 bits)
#pragma unroll
    for (int l=0;l<15;l++) feat[(size_t)l*npts + n] = __float_as_uint(h1[l+1]);
    feat[(size_t)15*npts + n] = __float_as_uint(sigma);
}

// ===================== K_pre: app_pre[a][o] = sum_j embed_a[a][j]*w_color0[o][31+j] =====================
__global__ void nerf_kpre(const float* __restrict__ embed_a,
                          const float* __restrict__ w_color0,
                          float* __restrict__ app_pre)
{
    int a = blockIdx.x;
    int o = threadIdx.x;   // 64
    const float* er = embed_a + (size_t)a*48;
    const float* wr = w_color0 + (size_t)o*103 + 31;
    float s = 0.f;
#pragma unroll
    for (int j=0;j<48;j++) s = fmaf(er[j], wr[j], s);
    app_pre[(size_t)a*64 + o] = s;
}

// ===================== K2: SH + color MLP =====================
__global__ __launch_bounds__(256, 2)
void nerf_k2(const float* __restrict__ x,
             const float* __restrict__ planes,
             const float* __restrict__ embed_a,
             const float* __restrict__ w_color0,
             const float* __restrict__ w_color1,
             const float* __restrict__ w_color2,
             const uint32_t* __restrict__ feat,
             const float* __restrict__ app_pre,   // may be null
             float* __restrict__ out, int npts)
{
    __shared__ float s_wc0T[103*64];
    __shared__ float s_wc1T[64*64];
    __shared__ float s_wc2T[64*4];

    for (int i = threadIdx.x; i < 103*64; i += 256){ int k=i>>6, o=i&63; s_wc0T[i] = w_color0[o*103+k]; }
    for (int i = threadIdx.x; i < 64*64;  i += 256){ int k=i>>6, o=i&63; s_wc1T[i] = w_color1[o*64+k]; }
    for (int i = threadIdx.x; i < 64*4;   i += 256){ int k=i>>2, o=i&3;  s_wc2T[i] = (o<3)? w_color2[o*64+k] : 0.f; }
    __syncthreads();

    int n = blockIdx.x*256 + threadIdx.x;
    if (n >= npts) return;

    const float* xr = x + (size_t)n*7;
    float dx=xr[3], dy=xr[4], dz=xr[5];
    float appf = xr[6];
    float p0=(xr[0]+1.f)*0.5f, p1=(xr[1]+1.f)*0.5f, p2=(xr[2]+1.f)*0.5f;

    // geo(15)+sigma from feat slots (coalesced per level-plane)
    float geo[15]; float sigma;
    {
        uint32_t g[16];
#pragma unroll
        for (int l=0;l<16;l++) g[l] = feat[(size_t)l*npts + n];
#pragma unroll
        for (int l=0;l<15;l++) geo[l] = __uint_as_float(g[l]);
        sigma = __uint_as_float(g[15]);
    }

    float acc[HID];
#pragma unroll
    for (int o=0;o<HID;o++) acc[o]=0.f;

    // SH(16)
    {
        float nrm = sqrtf(dx*dx+dy*dy+dz*dz);
        float sx=dx/nrm, sy=dy/nrm, sz=dz/nrm;
        float xx=sx*sx, yy=sy*sy, zz=sz*sz, xyv=sx*sy, yzv=sy*sz, xzv=sx*sz;
        float sh[16];
        sh[0]=0.28209479177387814f;
        sh[1]=-0.48860251190291987f*sy;
        sh[2]= 0.48860251190291987f*sz;
        sh[3]=-0.48860251190291987f*sx;
        sh[4]= 1.0925484305920792f*xyv;
        sh[5]=-1.0925484305920792f*yzv;
        sh[6]= 0.94617469575756f*zz-0.31539156525252005f;
        sh[7]=-1.0925484305920792f*xzv;
        sh[8]= 0.5462742152960396f*(xx-yy);
        sh[9]=-0.5900435899266435f*sy*(3.f*xx-yy);
        sh[10]=2.890611442640554f*xyv*sz;
        sh[11]=-0.4570457994644658f*sy*(4.f*zz-xx-yy);
        sh[12]=0.3731763325901154f*sz*(2.f*zz-3.f*xx-3.f*yy);
        sh[13]=-0.4570457994644658f*sx*(4.f*zz-xx-yy);
        sh[14]=1.445305721320277f*sz*(xx-yy);
        sh[15]=-0.5900435899266435f*sx*(xx-3.f*yy);
#pragma unroll
        for (int k=0;k<16;k++){
            AXPY64(acc, &s_wc0T[k*64], sh[k]);
        }
    }

#pragma unroll
    for (int j=0;j<15;j++){
        AXPY64(acc, &s_wc0T[(16+j)*64], geo[j]);
    }

    int ai = (int)appf;
    if (app_pre){
        const float* ap = app_pre + (size_t)ai*64;
#pragma unroll
        for (int o=0;o<64;o+=4){
            float4 v = ld4(ap+o);
            acc[o+0]+=v.x; acc[o+1]+=v.y; acc[o+2]+=v.z; acc[o+3]+=v.w;
        }
    } else {
        const float* ar = embed_a + (size_t)ai*48;
        for (int q=0;q<12;q++){
            float4 av = ld4(ar + q*4);
            const float* wc = &s_wc0T[(31+q*4)*64];
            AXPY64(acc, wc,       av.x);
            AXPY64(acc, wc+64,    av.y);
            AXPY64(acc, wc+128,   av.z);
            AXPY64(acc, wc+192,   av.w);
        }
    }

    {
        float pfv[24];
        plane_enc(planes, p0, p1, p2, pfv);
#pragma unroll
        for (int j=0;j<24;j++){
            AXPY64(acc, &s_wc0T[(79+j)*64], pfv[j]);
        }
    }

#pragma unroll
    for (int k=0;k<HID;k++) acc[k] = fmaxf(acc[k], 0.f);

    float c0a=0.f, c1a=0.f, c2a=0.f;
    {
        float acc2h[32];
#pragma unroll
        for (int o=0;o<32;o++) acc2h[o]=0.f;
#pragma unroll
        for (int k=0;k<HID;k++){
            AXPY32(acc2h, &s_wc1T[k*64], acc[k]);
        }
#pragma unroll
        for (int o=0;o<32;o++){
            float v = fmaxf(acc2h[o], 0.f);
            float4 w = ld4(&s_wc2T[o*4]);
            c0a=fmaf(w.x,v,c0a); c1a=fmaf(w.y,v,c1a); c2a=fmaf(w.z,v,c2a);
        }
    }
    {
        float acc2h[32];
#pragma unroll
        for (int o=0;o<32;o++) acc2h[o]=0.f;
#pragma unroll
        for (int k=0;k<HID;k++){
            AXPY32(acc2h, &s_wc1T[k*64+32], acc[k]);
        }
#pragma unroll
        for (int o=0;o<32;o++){
            float v = fmaxf(acc2h[o], 0.f);
            float4 w = ld4(&s_wc2T[(32+o)*4]);
            c0a=fmaf(w.x,v,c0a); c1a=fmaf(w.y,v,c1a); c2a=fmaf(w.z,v,c2a);
        }
    }

    float4 o4;
    o4.x = 1.f/(1.f+expf(-c0a));
    o4.y = 1.f/(1.f+expf(-c1a));
    o4.z = 1.f/(1.f+expf(-c2a));
    o4.w = sigma;
    *reinterpret_cast<float4*>(out + (size_t)n*4) = o4;
}

// ===================== fallback single kernel (used only if ws too small) =====================
__global__ __launch_bounds__(256, 1)
void nerf_fwd(const float* __restrict__ x,
              const float* __restrict__ hash_tables,
              const float* __restrict__ planes,
              const float* __restrict__ embed_a,
              const float* __restrict__ w_sigma0,
              const float* __restrict__ w_sigma1,
              const float* __restrict__ w_color0,
              const float* __restrict__ w_color1,
              const float* __restrict__ w_color2,
              float* __restrict__ out,
              ResArr res, int npts)
{
    __shared__ float s_ws0T[56*64];
    __shared__ float s_ws1T[64*16];
    __shared__ float s_wc0T[103*64];
    __shared__ float s_wc1T[64*64];
    __shared__ float s_wc2T[64*4];

    for (int i = threadIdx.x; i < 56*64;  i += 256){ int k=i>>6, o=i&63; s_ws0T[i] = w_sigma0[o*56+k]; }
    for (int i = threadIdx.x; i < 64*16;  i += 256){ int k=i>>4, j=i&15; s_ws1T[i] = w_sigma1[j*64+k]; }
    for (int i = threadIdx.x; i < 103*64; i += 256){ int k=i>>6, o=i&63; s_wc0T[i] = w_color0[o*103+k]; }
    for (int i = threadIdx.x; i < 64*64;  i += 256){ int k=i>>6, o=i&63; s_wc1T[i] = w_color1[o*64+k]; }
    for (int i = threadIdx.x; i < 64*4;   i += 256){ int k=i>>2, o=i&3;  s_wc2T[i] = (o<3)? w_color2[o*64+k] : 0.f; }
    __syncthreads();

    int n = blockIdx.x*256 + threadIdx.x;
    if (n >= npts) return;

    const float* xr = x + (size_t)n*7;
    float px=xr[0], py=xr[1], pz=xr[2];
    float dx=xr[3], dy=xr[4], dz=xr[5];
    float appf = xr[6];
    float p0=(px+1.f)*0.5f, p1=(py+1.f)*0.5f, p2=(pz+1.f)*0.5f;

    float acc[HID];
#pragma unroll
    for (int o=0;o<HID;o++) acc[o]=0.f;

    const float2* tabs = reinterpret_cast<const float2*>(hash_tables);
    for (int l=0; l<NLEV; l++){
        float R = res.v[l];
        float ax=p0*R, ay=p1*R, az=p2*R;
        float fx=floorf(ax), fy=floorf(ay), fz=floorf(az);
        float rx=ax-fx, ry=ay-fy, rz=az-fz;
        uint32_t ix=(uint32_t)fx, iy=(uint32_t)fy, iz=(uint32_t)fz;
        const float2* tab = tabs + (size_t)l*TSIZE;
        uint32_t hx0=ix,               hx1=ix+1u;
        uint32_t hy0=iy*2654435761u,   hy1=(iy+1u)*2654435761u;
        uint32_t hz0=iz*805459861u,    hz1=(iz+1u)*805459861u;
        float wx0=1.f-rx, wx1=rx, wy0=1.f-ry, wy1=ry, wz0=1.f-rz, wz1=rz;
        float f0=0.f, f1=0.f;
#pragma unroll
        for (int c=0;c<8;c++){
            uint32_t hxx=(c&4)?hx1:hx0;
            uint32_t hyy=(c&2)?hy1:hy0;
            uint32_t hzz=(c&1)?hz1:hz0;
            uint32_t idx=(hxx^hyy^hzz)&(TSIZE-1u);
            float2 t = tab[idx];
            float w = ((c&4)?wx1:wx0)*((c&2)?wy1:wy0)*((c&1)?wz1:wz0);
            f0 = fmaf(w,t.x,f0);
            f1 = fmaf(w,t.y,f1);
        }
        AXPY64(acc, &s_ws0T[(2*l+0)*64], f0);
        AXPY64(acc, &s_ws0T[(2*l+1)*64], f1);
    }

    float pfv[24];
    plane_enc(planes, p0, p1, p2, pfv);
#pragma unroll
    for (int j=0;j<24;j++){
        AXPY64(acc, &s_ws0T[(32+j)*64], pfv[j]);
    }

    float h1[16];
#pragma unroll
    for (int j=0;j<16;j++) h1[j]=0.f;
#pragma unroll
    for (int k=0;k<HID;k++){
        float v = fmaxf(acc[k], 0.f);
        const float* wr = &s_ws1T[k*16];
#pragma unroll
        for (int j=0;j<16;j+=4){
            float4 w=ld4(wr+j);
            h1[j+0]=fmaf(w.x,v,h1[j+0]); h1[j+1]=fmaf(w.y,v,h1[j+1]);
            h1[j+2]=fmaf(w.z,v,h1[j+2]); h1[j+3]=fmaf(w.w,v,h1[j+3]);
        }
    }
    float sg = fminf(fmaxf(h1[0], -15.f), 15.f);
    float sigma = expf(sg);

#pragma unroll
    for (int o=0;o<HID;o++) acc[o]=0.f;

    float nrm = sqrtf(dx*dx+dy*dy+dz*dz);
    float sx=dx/nrm, sy=dy/nrm, sz=dz/nrm;
    float xx=sx*sx, yy=sy*sy, zz=sz*sz, xyv=sx*sy, yzv=sy*sz, xzv=sx*sz;
    float sh[16];
    sh[0]=0.28209479177387814f;
    sh[1]=-0.48860251190291987f*sy;
    sh[2]= 0.48860251190291987f*sz;
    sh[3]=-0.48860251190291987f*sx;
    sh[4]= 1.0925484305920792f*xyv;
    sh[5]=-1.0925484305920792f*yzv;
    sh[6]= 0.94617469575756f*zz-0.31539156525252005f;
    sh[7]=-1.0925484305920792f*xzv;
    sh[8]= 0.5462742152960396f*(xx-yy);
    sh[9]=-0.5900435899266435f*sy*(3.f*xx-yy);
    sh[10]=2.890611442640554f*xyv*sz;
    sh[11]=-0.4570457994644658f*sy*(4.f*zz-xx-yy);
    sh[12]=0.3731763325901154f*sz*(2.f*zz-3.f*xx-3.f*yy);
    sh[13]=-0.4570457994644658f*sx*(4.f*zz-xx-yy);
    sh[14]=1.445305721320277f*sz*(xx-yy);
    sh[15]=-0.5900435899266435f*sx*(xx-3.f*yy);
#pragma unroll
    for (int k=0;k<16;k++){
        AXPY64(acc, &s_wc0T[k*64], sh[k]);
    }
#pragma unroll
    for (int j=0;j<15;j++){
        AXPY64(acc, &s_wc0T[(16+j)*64], h1[1+j]);
    }
    {
        int ai = (int)appf;
        const float* ar = embed_a + (size_t)ai*48;
        for (int q=0;q<12;q++){
            float4 av = ld4(ar + q*4);
            const float* wc = &s_wc0T[(31+q*4)*64];
            AXPY64(acc, wc,       av.x);
            AXPY64(acc, wc+64,    av.y);
            AXPY64(acc, wc+128,   av.z);
            AXPY64(acc, wc+192,   av.w);
        }
    }
#pragma unroll
    for (int j=0;j<24;j++){
        AXPY64(acc, &s_wc0T[(79+j)*64], pfv[j]);
    }

    float acc2[HID];
#pragma unroll
    for (int o=0;o<HID;o++) acc2[o]=0.f;
#pragma unroll
    for (int k=0;k<HID;k++){
        float v = fmaxf(acc[k], 0.f);
        AXPY64(acc2, &s_wc1T[k*64], v);
    }

    float c0a=0.f, c1a=0.f, c2a=0.f;
#pragma unroll
    for (int k=0;k<HID;k++){
        float v = fmaxf(acc2[k], 0.f);
        float4 w = ld4(&s_wc2T[k*4]);
        c0a=fmaf(w.x,v,c0a); c1a=fmaf(w.y,v,c1a); c2a=fmaf(w.z,v,c2a);
    }
    float4 o4;
    o4.x = 1.f/(1.f+expf(-c0a));
    o4.y = 1.f/(1.f+expf(-c1a));
    o4.z = 1.f/(1.f+expf(-c2a));
    o4.w = sigma;
    *reinterpret_cast<float4*>(out + (size_t)n*4) = o4;
}

extern "C" void kernel_launch(void* const* d_in, const int* in_sizes, int n_in,
                              void* d_out, int out_size, void* d_ws, size_t ws_size,
                              hipStream_t stream) {
    const float* x        = (const float*)d_in[0];
    const float* ht       = (const float*)d_in[1];
    const float* planes   = (const float*)d_in[2];
    const float* embed_a  = (const float*)d_in[3];
    const float* w_sigma0 = (const float*)d_in[4];
    const float* w_sigma1 = (const float*)d_in[5];
    const float* w_color0 = (const float*)d_in[6];
    const float* w_color1 = (const float*)d_in[7];
    const float* w_color2 = (const float*)d_in[8];
    float* out = (float*)d_out;

    int npts = in_sizes[0] / 7;

    // Replicate numpy's RES bit-exactly (same libm chain).
    ResArr res;
    double b = exp((log(2048.0) - log(16.0)) / 15.0);
    for (int l=0; l<NLEV; l++)
        res.v[l] = (float)floor(16.0 * pow(b, (double)l));

    size_t feat_bytes = (size_t)npts * 16 * sizeof(uint32_t);   // 64 MB @ 1M pts
    size_t pre_bytes  = (size_t)1024 * 64 * sizeof(float);      // 256 KB

    if (ws_size >= feat_bytes) {
        uint32_t* feat = (uint32_t*)d_ws;
        float* app_pre = nullptr;
        bool use_pre = (ws_size >= feat_bytes + pre_bytes);
        if (use_pre) app_pre = (float*)((char*)d_ws + feat_bytes);

        int chunks = (npts + 511) / 512;
        hipLaunchKernelGGL(nerf_k0, dim3(16*chunks), dim3(256), 0, stream,
                           x, ht, feat, res, npts);
        int g = (npts + 255) / 256;
        hipLaunchKernelGGL(nerf_k1b, dim3(g), dim3(256), 0, stream,
                           x, planes, feat, w_sigma0, w_sigma1, npts);
        if (use_pre)
            hipLaunchKernelGGL(nerf_kpre, dim3(1024), dim3(64), 0, stream,
                               embed_a, w_color0, app_pre);
        hipLaunchKernelGGL(nerf_k2, dim3(g), dim3(256), 0, stream,
                           x, planes, embed_a, w_color0, w_color1, w_color2,
                           feat, app_pre, out, npts);
    } else {
        int grid = (npts + 255) / 256;
        hipLaunchKernelGGL(nerf_fwd, dim3(grid), dim3(256), 0, stream,
                           x, ht, planes, embed_a,
                           w_sigma0, w_sigma1, w_color0, w_color1, w_color2,
                           out, res, npts);
    }
}

// Round 6
// 1267.517 us; speedup vs baseline: 1.6113x; 1.0528x over previous
//
#include <hip/hip_runtime.h>
#include <cmath>
#include <stdint.h>

#define NLEV  16
#define TSIZE (1u<<19)
#define PRES  512
#define PFD   8
#define HID   64

struct ResArr { float v[NLEV]; };

__device__ __forceinline__ float4 ld4(const float* p){ return *reinterpret_cast<const float4*>(p); }

__device__ __forceinline__ uint16_t f2bf(float f){
    uint32_t u = __float_as_uint(f);
    uint32_t r = (u + 0x7FFFu + ((u>>16)&1u)) >> 16;
    return (uint16_t)r;
}
__device__ __forceinline__ float bf2f(uint32_t h){ return __uint_as_float(h<<16); }

// acc[o] += wT_col[o] * v  for o=0..63, static indexing only
#define AXPY64(A, WPTR, V) do { const float* _w=(WPTR); const float _v=(V); \
  _Pragma("unroll") \
  for (int _o=0;_o<64;_o+=4){ float4 _w4=ld4(_w+_o); \
    A[_o+0]=fmaf(_w4.x,_v,A[_o+0]); A[_o+1]=fmaf(_w4.y,_v,A[_o+1]); \
    A[_o+2]=fmaf(_w4.z,_v,A[_o+2]); A[_o+3]=fmaf(_w4.w,_v,A[_o+3]); } } while(0)

#define AXPY32(A, WPTR, V) do { const float* _w=(WPTR); const float _v=(V); \
  _Pragma("unroll") \
  for (int _o=0;_o<32;_o+=4){ float4 _w4=ld4(_w+_o); \
    A[_o+0]=fmaf(_w4.x,_v,A[_o+0]); A[_o+1]=fmaf(_w4.y,_v,A[_o+1]); \
    A[_o+2]=fmaf(_w4.z,_v,A[_o+2]); A[_o+3]=fmaf(_w4.w,_v,A[_o+3]); } } while(0)

__device__ __forceinline__ void plane_enc(const float* __restrict__ planes,
                                          float p0, float p1, float p2, float* pfv)
{
#pragma unroll
    for (int i=0;i<3;i++){
        float ua = (i==2? p1 : p0)*511.f;
        float va = (i==0? p1 : p2)*511.f;
        float uf=floorf(ua), vf=floorf(va);
        float wu=ua-uf, wv=va-vf;
        int u0=(int)uf; u0 = u0<0?0:(u0>510?510:u0);
        int v0=(int)vf; v0 = v0<0?0:(v0>510?510:v0);
        const float* pl = planes + ((size_t)i*PRES*PRES + (size_t)(u0*PRES+v0))*PFD;
        float4 a0=ld4(pl),              a1=ld4(pl+4);
        float4 b0=ld4(pl+PFD),          b1=ld4(pl+PFD+4);
        float4 c0=ld4(pl+PRES*PFD),     c1=ld4(pl+PRES*PFD+4);
        float4 d0=ld4(pl+PRES*PFD+PFD), d1=ld4(pl+PRES*PFD+PFD+4);
        float w00=(1.f-wu)*(1.f-wv), w01=(1.f-wu)*wv, w10=wu*(1.f-wv), w11=wu*wv;
        pfv[i*8+0]=a0.x*w00+b0.x*w01+c0.x*w10+d0.x*w11;
        pfv[i*8+1]=a0.y*w00+b0.y*w01+c0.y*w10+d0.y*w11;
        pfv[i*8+2]=a0.z*w00+b0.z*w01+c0.z*w10+d0.z*w11;
        pfv[i*8+3]=a0.w*w00+b0.w*w01+c0.w*w10+d0.w*w11;
        pfv[i*8+4]=a1.x*w00+b1.x*w01+c1.x*w10+d1.x*w11;
        pfv[i*8+5]=a1.y*w00+b1.y*w01+c1.y*w10+d1.y*w11;
        pfv[i*8+6]=a1.z*w00+b1.z*w01+c1.z*w10+d1.z*w11;
        pfv[i*8+7]=a1.w*w00+b1.w*w01+c1.w*w10+d1.w*w11;
    }
}

// ===================== K0: level-major hash gather, XCD-pinned =====================
// Launched TWICE (lvl_base = 0 then 8); level = lvl_base + (bid&7) so XCD k's L2
// temporally holds exactly ONE 4MB level table (16 levels / 8 XCDs / 2 passes).
__global__ __launch_bounds__(256, 2)
void nerf_k0(const float* __restrict__ x,
             const float* __restrict__ hash_tables,
             uint32_t* __restrict__ feat,
             ResArr res, int npts, int lvl_base)
{
    int bid   = blockIdx.x;
    int level = lvl_base + (bid & 7);
    int chunk = bid >> 3;
    int n0 = chunk*512 + threadIdx.x;
    int n1 = n0 + 256;
    float R = res.v[level];
    const float2* tab = reinterpret_cast<const float2*>(hash_tables) + (size_t)level*TSIZE;

    bool v0ok = (n0 < npts), v1ok = (n1 < npts);

    float p0a=0,p1a=0,p2a=0, p0b=0,p1b=0,p2b=0;
    if (v0ok){ const float* xr = x + (size_t)n0*7;
        p0a=(xr[0]+1.f)*0.5f; p1a=(xr[1]+1.f)*0.5f; p2a=(xr[2]+1.f)*0.5f; }
    if (v1ok){ const float* xr = x + (size_t)n1*7;
        p0b=(xr[0]+1.f)*0.5f; p1b=(xr[1]+1.f)*0.5f; p2b=(xr[2]+1.f)*0.5f; }

    float axa=p0a*R, aya=p1a*R, aza=p2a*R;
    float fxa=floorf(axa), fya=floorf(aya), fza=floorf(aza);
    float rxa=axa-fxa, rya=aya-fya, rza=aza-fza;
    uint32_t ixa=(uint32_t)fxa, iya=(uint32_t)fya, iza=(uint32_t)fza;
    uint32_t hx0a=ixa,             hx1a=ixa+1u;
    uint32_t hy0a=iya*2654435761u, hy1a=(iya+1u)*2654435761u;
    uint32_t hz0a=iza*805459861u,  hz1a=(iza+1u)*805459861u;

    float axb=p0b*R, ayb=p1b*R, azb=p2b*R;
    float fxb=floorf(axb), fyb=floorf(ayb), fzb=floorf(azb);
    float rxb=axb-fxb, ryb=ayb-fyb, rzb=azb-fzb;
    uint32_t ixb=(uint32_t)fxb, iyb=(uint32_t)fyb, izb=(uint32_t)fzb;
    uint32_t hx0b=ixb,             hx1b=ixb+1u;
    uint32_t hy0b=iyb*2654435761u, hy1b=(iyb+1u)*2654435761u;
    uint32_t hz0b=izb*805459861u,  hz1b=(izb+1u)*805459861u;

    float2 ta[8], tb[8];
#pragma unroll
    for (int c=0;c<8;c++){
        uint32_t idx = (((c&4)?hx1a:hx0a) ^ ((c&2)?hy1a:hy0a) ^ ((c&1)?hz1a:hz0a)) & (TSIZE-1u);
        ta[c] = tab[idx];
    }
#pragma unroll
    for (int c=0;c<8;c++){
        uint32_t idx = (((c&4)?hx1b:hx0b) ^ ((c&2)?hy1b:hy0b) ^ ((c&1)?hz1b:hz0b)) & (TSIZE-1u);
        tb[c] = tab[idx];
    }

    float wxa0=1.f-rxa, wya0=1.f-rya, wza0=1.f-rza;
    float f0a=0.f, f1a=0.f;
#pragma unroll
    for (int c=0;c<8;c++){
        float w = ((c&4)?rxa:wxa0)*((c&2)?rya:wya0)*((c&1)?rza:wza0);
        f0a = fmaf(w,ta[c].x,f0a); f1a = fmaf(w,ta[c].y,f1a);
    }
    float wxb0=1.f-rxb, wyb0=1.f-ryb, wzb0=1.f-rzb;
    float f0b=0.f, f1b=0.f;
#pragma unroll
    for (int c=0;c<8;c++){
        float w = ((c&4)?rxb:wxb0)*((c&2)?ryb:wyb0)*((c&1)?rzb:wzb0);
        f0b = fmaf(w,tb[c].x,f0b); f1b = fmaf(w,tb[c].y,f1b);
    }

    size_t base = (size_t)level*npts;
    if (v0ok) feat[base+n0] = (uint32_t)f2bf(f0a) | ((uint32_t)f2bf(f1a)<<16);
    if (v1ok) feat[base+n1] = (uint32_t)f2bf(f0b) | ((uint32_t)f2bf(f1b)<<16);
}

// ===================== ktrans: transpose weights into ws (wT[k][o]) =====================
__global__ void nerf_ktrans(const float* __restrict__ w_sigma0,
                            const float* __restrict__ w_sigma1,
                            const float* __restrict__ w_color0,
                            const float* __restrict__ w_color1,
                            const float* __restrict__ w_color2,
                            float* __restrict__ t_s0, float* __restrict__ t_s1,
                            float* __restrict__ t_c0, float* __restrict__ t_c1,
                            float* __restrict__ t_c2)
{
    int tid = threadIdx.x;
    for (int i=tid;i<56*64; i+=256){ int k=i>>6,o=i&63; t_s0[i]=w_sigma0[o*56+k]; }
    for (int i=tid;i<64*16; i+=256){ int k=i>>4,j=i&15; t_s1[i]=w_sigma1[j*64+k]; }
    for (int i=tid;i<103*64;i+=256){ int k=i>>6,o=i&63; t_c0[i]=w_color0[o*103+k]; }
    for (int i=tid;i<64*64; i+=256){ int k=i>>6,o=i&63; t_c1[i]=w_color1[o*64+k]; }
    for (int i=tid;i<64*4;  i+=256){ int k=i>>2,o=i&3;  t_c2[i]=(o<3)?w_color2[o*64+k]:0.f; }
}

// ===================== kpre: app_pre[a][o] = sum_j embed_a[a][j]*w_color0[o][31+j] =====================
__global__ void nerf_kpre(const float* __restrict__ embed_a,
                          const float* __restrict__ w_color0,
                          float* __restrict__ app_pre)
{
    int a = blockIdx.x;
    int o = threadIdx.x;   // 64
    const float* er = embed_a + (size_t)a*48;
    const float* wr = w_color0 + (size_t)o*103 + 31;
    float s = 0.f;
#pragma unroll
    for (int j=0;j<48;j++) s = fmaf(er[j], wr[j], s);
    app_pre[(size_t)a*64 + o] = s;
}

// ===================== K1s: sigma MLP, weights via uniform global (SMEM) loads =====================
__global__ __launch_bounds__(256, 2)
void nerf_k1s(const float* __restrict__ x,
              const float* __restrict__ planes,
              uint32_t* __restrict__ feat,
              const float* __restrict__ wT_s0,
              const float* __restrict__ wT_s1,
              int npts)
{
    int n = blockIdx.x*256 + threadIdx.x;
    if (n >= npts) return;

    uint32_t fl[NLEV];
#pragma unroll
    for (int l=0;l<NLEV;l++) fl[l] = feat[(size_t)l*npts + n];

    float acc[HID];
#pragma unroll
    for (int o=0;o<HID;o++) acc[o]=0.f;

#pragma unroll
    for (int l=0;l<NLEV;l++){
        float f0 = bf2f(fl[l] & 0xFFFFu);
        float f1 = bf2f(fl[l] >> 16);
        AXPY64(acc, &wT_s0[(2*l+0)*64], f0);
        AXPY64(acc, &wT_s0[(2*l+1)*64], f1);
    }

    const float* xr = x + (size_t)n*7;
    float p0=(xr[0]+1.f)*0.5f, p1=(xr[1]+1.f)*0.5f, p2=(xr[2]+1.f)*0.5f;
    float pfv[24];
    plane_enc(planes, p0, p1, p2, pfv);
#pragma unroll
    for (int j=0;j<24;j++){
        AXPY64(acc, &wT_s0[(32+j)*64], pfv[j]);
    }

    float h1[16];
#pragma unroll
    for (int j=0;j<16;j++) h1[j]=0.f;
#pragma unroll
    for (int k=0;k<HID;k++){
        float v = fmaxf(acc[k], 0.f);
        const float* wr = &wT_s1[k*16];
#pragma unroll
        for (int j=0;j<16;j+=4){
            float4 w=ld4(wr+j);
            h1[j+0]=fmaf(w.x,v,h1[j+0]); h1[j+1]=fmaf(w.y,v,h1[j+1]);
            h1[j+2]=fmaf(w.z,v,h1[j+2]); h1[j+3]=fmaf(w.w,v,h1[j+3]);
        }
    }
    float sg = fminf(fmaxf(h1[0], -15.f), 15.f);
    float sigma = expf(sg);

#pragma unroll
    for (int l=0;l<15;l++) feat[(size_t)l*npts + n] = __float_as_uint(h1[l+1]);
    feat[(size_t)15*npts + n] = __float_as_uint(sigma);
}

// ===================== K2s: SH + color MLP, SMEM weights =====================
__global__ __launch_bounds__(256, 2)
void nerf_k2s(const float* __restrict__ x,
              const float* __restrict__ planes,
              const float* __restrict__ wT_c0,
              const float* __restrict__ wT_c1,
              const float* __restrict__ wT_c2,
              const uint32_t* __restrict__ feat,
              const float* __restrict__ app_pre,
              float* __restrict__ out, int npts)
{
    int n = blockIdx.x*256 + threadIdx.x;
    if (n >= npts) return;

    const float* xr = x + (size_t)n*7;
    float dx=xr[3], dy=xr[4], dz=xr[5];
    float appf = xr[6];
    float p0=(xr[0]+1.f)*0.5f, p1=(xr[1]+1.f)*0.5f, p2=(xr[2]+1.f)*0.5f;

    float geo[15]; float sigma;
    {
        uint32_t g[16];
#pragma unroll
        for (int l=0;l<16;l++) g[l] = feat[(size_t)l*npts + n];
#pragma unroll
        for (int l=0;l<15;l++) geo[l] = __uint_as_float(g[l]);
        sigma = __uint_as_float(g[15]);
    }

    float acc[HID];
    // init acc with app_pre contribution (gathered, 64 floats)
    {
        int ai = (int)appf;
        const float* ap = app_pre + (size_t)ai*64;
#pragma unroll
        for (int o=0;o<HID;o+=4){
            float4 v = ld4(ap+o);
            acc[o+0]=v.x; acc[o+1]=v.y; acc[o+2]=v.z; acc[o+3]=v.w;
        }
    }

    // SH(16)
    {
        float nrm = sqrtf(dx*dx+dy*dy+dz*dz);
        float sx=dx/nrm, sy=dy/nrm, sz=dz/nrm;
        float xx=sx*sx, yy=sy*sy, zz=sz*sz, xyv=sx*sy, yzv=sy*sz, xzv=sx*sz;
        float sh[16];
        sh[0]=0.28209479177387814f;
        sh[1]=-0.48860251190291987f*sy;
        sh[2]= 0.48860251190291987f*sz;
        sh[3]=-0.48860251190291987f*sx;
        sh[4]= 1.0925484305920792f*xyv;
        sh[5]=-1.0925484305920792f*yzv;
        sh[6]= 0.94617469575756f*zz-0.31539156525252005f;
        sh[7]=-1.0925484305920792f*xzv;
        sh[8]= 0.5462742152960396f*(xx-yy);
        sh[9]=-0.5900435899266435f*sy*(3.f*xx-yy);
        sh[10]=2.890611442640554f*xyv*sz;
        sh[11]=-0.4570457994644658f*sy*(4.f*zz-xx-yy);
        sh[12]=0.3731763325901154f*sz*(2.f*zz-3.f*xx-3.f*yy);
        sh[13]=-0.4570457994644658f*sx*(4.f*zz-xx-yy);
        sh[14]=1.445305721320277f*sz*(xx-yy);
        sh[15]=-0.5900435899266435f*sx*(xx-3.f*yy);
#pragma unroll
        for (int k=0;k<16;k++){
            AXPY64(acc, &wT_c0[k*64], sh[k]);
        }
    }

#pragma unroll
    for (int j=0;j<15;j++){
        AXPY64(acc, &wT_c0[(16+j)*64], geo[j]);
    }

    {
        float pfv[24];
        plane_enc(planes, p0, p1, p2, pfv);
#pragma unroll
        for (int j=0;j<24;j++){
            AXPY64(acc, &wT_c0[(79+j)*64], pfv[j]);
        }
    }

#pragma unroll
    for (int k=0;k<HID;k++) acc[k] = fmaxf(acc[k], 0.f);

    float c0a=0.f, c1a=0.f, c2a=0.f;
    {
        float acc2h[32];
#pragma unroll
        for (int o=0;o<32;o++) acc2h[o]=0.f;
#pragma unroll
        for (int k=0;k<HID;k++){
            AXPY32(acc2h, &wT_c1[k*64], acc[k]);
        }
#pragma unroll
        for (int o=0;o<32;o++){
            float v = fmaxf(acc2h[o], 0.f);
            float4 w = ld4(&wT_c2[o*4]);
            c0a=fmaf(w.x,v,c0a); c1a=fmaf(w.y,v,c1a); c2a=fmaf(w.z,v,c2a);
        }
    }
    {
        float acc2h[32];
#pragma unroll
        for (int o=0;o<32;o++) acc2h[o]=0.f;
#pragma unroll
        for (int k=0;k<HID;k++){
            AXPY32(acc2h, &wT_c1[k*64+32], acc[k]);
        }
#pragma unroll
        for (int o=0;o<32;o++){
            float v = fmaxf(acc2h[o], 0.f);
            float4 w = ld4(&wT_c2[(32+o)*4]);
            c0a=fmaf(w.x,v,c0a); c1a=fmaf(w.y,v,c1a); c2a=fmaf(w.z,v,c2a);
        }
    }

    float4 o4;
    o4.x = 1.f/(1.f+expf(-c0a));
    o4.y = 1.f/(1.f+expf(-c1a));
    o4.z = 1.f/(1.f+expf(-c2a));
    o4.w = sigma;
    *reinterpret_cast<float4*>(out + (size_t)n*4) = o4;
}

// ===================== fallback single kernel (used only if ws too small) =====================
__global__ __launch_bounds__(256, 1)
void nerf_fwd(const float* __restrict__ x,
              const float* __restrict__ hash_tables,
              const float* __restrict__ planes,
              const float* __restrict__ embed_a,
              const float* __restrict__ w_sigma0,
              const float* __restrict__ w_sigma1,
              const float* __restrict__ w_color0,
              const float* __restrict__ w_color1,
              const float* __restrict__ w_color2,
              float* __restrict__ out,
              ResArr res, int npts)
{
    __shared__ float s_ws0T[56*64];
    __shared__ float s_ws1T[64*16];
    __shared__ float s_wc0T[103*64];
    __shared__ float s_wc1T[64*64];
    __shared__ float s_wc2T[64*4];

    for (int i = threadIdx.x; i < 56*64;  i += 256){ int k=i>>6, o=i&63; s_ws0T[i] = w_sigma0[o*56+k]; }
    for (int i = threadIdx.x; i < 64*16;  i += 256){ int k=i>>4, j=i&15; s_ws1T[i] = w_sigma1[j*64+k]; }
    for (int i = threadIdx.x; i < 103*64; i += 256){ int k=i>>6, o=i&63; s_wc0T[i] = w_color0[o*103+k]; }
    for (int i = threadIdx.x; i < 64*64;  i += 256){ int k=i>>6, o=i&63; s_wc1T[i] = w_color1[o*64+k]; }
    for (int i = threadIdx.x; i < 64*4;   i += 256){ int k=i>>2, o=i&3;  s_wc2T[i] = (o<3)? w_color2[o*64+k] : 0.f; }
    __syncthreads();

    int n = blockIdx.x*256 + threadIdx.x;
    if (n >= npts) return;

    const float* xr = x + (size_t)n*7;
    float px=xr[0], py=xr[1], pz=xr[2];
    float dx=xr[3], dy=xr[4], dz=xr[5];
    float appf = xr[6];
    float p0=(px+1.f)*0.5f, p1=(py+1.f)*0.5f, p2=(pz+1.f)*0.5f;

    float acc[HID];
#pragma unroll
    for (int o=0;o<HID;o++) acc[o]=0.f;

    const float2* tabs = reinterpret_cast<const float2*>(hash_tables);
    for (int l=0; l<NLEV; l++){
        float R = res.v[l];
        float ax=p0*R, ay=p1*R, az=p2*R;
        float fx=floorf(ax), fy=floorf(ay), fz=floorf(az);
        float rx=ax-fx, ry=ay-fy, rz=az-fz;
        uint32_t ix=(uint32_t)fx, iy=(uint32_t)fy, iz=(uint32_t)fz;
        const float2* tab = tabs + (size_t)l*TSIZE;
        uint32_t hx0=ix,               hx1=ix+1u;
        uint32_t hy0=iy*2654435761u,   hy1=(iy+1u)*2654435761u;
        uint32_t hz0=iz*805459861u,    hz1=(iz+1u)*805459861u;
        float wx0=1.f-rx, wx1=rx, wy0=1.f-ry, wy1=ry, wz0=1.f-rz, wz1=rz;
        float f0=0.f, f1=0.f;
#pragma unroll
        for (int c=0;c<8;c++){
            uint32_t hxx=(c&4)?hx1:hx0;
            uint32_t hyy=(c&2)?hy1:hy0;
            uint32_t hzz=(c&1)?hz1:hz0;
            uint32_t idx=(hxx^hyy^hzz)&(TSIZE-1u);
            float2 t = tab[idx];
            float w = ((c&4)?wx1:wx0)*((c&2)?wy1:wy0)*((c&1)?wz1:wz0);
            f0 = fmaf(w,t.x,f0);
            f1 = fmaf(w,t.y,f1);
        }
        AXPY64(acc, &s_ws0T[(2*l+0)*64], f0);
        AXPY64(acc, &s_ws0T[(2*l+1)*64], f1);
    }

    float pfv[24];
    plane_enc(planes, p0, p1, p2, pfv);
#pragma unroll
    for (int j=0;j<24;j++){
        AXPY64(acc, &s_ws0T[(32+j)*64], pfv[j]);
    }

    float h1[16];
#pragma unroll
    for (int j=0;j<16;j++) h1[j]=0.f;
#pragma unroll
    for (int k=0;k<HID;k++){
        float v = fmaxf(acc[k], 0.f);
        const float* wr = &s_ws1T[k*16];
#pragma unroll
        for (int j=0;j<16;j+=4){
            float4 w=ld4(wr+j);
            h1[j+0]=fmaf(w.x,v,h1[j+0]); h1[j+1]=fmaf(w.y,v,h1[j+1]);
            h1[j+2]=fmaf(w.z,v,h1[j+2]); h1[j+3]=fmaf(w.w,v,h1[j+3]);
        }
    }
    float sg = fminf(fmaxf(h1[0], -15.f), 15.f);
    float sigma = expf(sg);

#pragma unroll
    for (int o=0;o<HID;o++) acc[o]=0.f;

    float nrm = sqrtf(dx*dx+dy*dy+dz*dz);
    float sx=dx/nrm, sy=dy/nrm, sz=dz/nrm;
    float xx=sx*sx, yy=sy*sy, zz=sz*sz, xyv=sx*sy, yzv=sy*sz, xzv=sx*sz;
    float sh[16];
    sh[0]=0.28209479177387814f;
    sh[1]=-0.48860251190291987f*sy;
    sh[2]= 0.48860251190291987f*sz;
    sh[3]=-0.48860251190291987f*sx;
    sh[4]= 1.0925484305920792f*xyv;
    sh[5]=-1.0925484305920792f*yzv;
    sh[6]= 0.94617469575756f*zz-0.31539156525252005f;
    sh[7]=-1.0925484305920792f*xzv;
    sh[8]= 0.5462742152960396f*(xx-yy);
    sh[9]=-0.5900435899266435f*sy*(3.f*xx-yy);
    sh[10]=2.890611442640554f*xyv*sz;
    sh[11]=-0.4570457994644658f*sy*(4.f*zz-xx-yy);
    sh[12]=0.3731763325901154f*sz*(2.f*zz-3.f*xx-3.f*yy);
    sh[13]=-0.4570457994644658f*sx*(4.f*zz-xx-yy);
    sh[14]=1.445305721320277f*sz*(xx-yy);
    sh[15]=-0.5900435899266435f*sx*(xx-3.f*yy);
#pragma unroll
    for (int k=0;k<16;k++){
        AXPY64(acc, &s_wc0T[k*64], sh[k]);
    }
#pragma unroll
    for (int j=0;j<15;j++){
        AXPY64(acc, &s_wc0T[(16+j)*64], h1[1+j]);
    }
    {
        int ai = (int)appf;
        const float* ar = embed_a + (size_t)ai*48;
        for (int q=0;q<12;q++){
            float4 av = ld4(ar + q*4);
            const float* wc = &s_wc0T[(31+q*4)*64];
            AXPY64(acc, wc,       av.x);
            AXPY64(acc, wc+64,    av.y);
            AXPY64(acc, wc+128,   av.z);
            AXPY64(acc, wc+192,   av.w);
        }
    }
#pragma unroll
    for (int j=0;j<24;j++){
        AXPY64(acc, &s_wc0T[(79+j)*64], pfv[j]);
    }

    float acc2[HID];
#pragma unroll
    for (int o=0;o<HID;o++) acc2[o]=0.f;
#pragma unroll
    for (int k=0;k<HID;k++){
        float v = fmaxf(acc[k], 0.f);
        AXPY64(acc2, &s_wc1T[k*64], v);
    }

    float c0a=0.f, c1a=0.f, c2a=0.f;
#pragma unroll
    for (int k=0;k<HID;k++){
        float v = fmaxf(acc2[k], 0.f);
        float4 w = ld4(&s_wc2T[k*4]);
        c0a=fmaf(w.x,v,c0a); c1a=fmaf(w.y,v,c1a); c2a=fmaf(w.z,v,c2a);
    }
    float4 o4;
    o4.x = 1.f/(1.f+expf(-c0a));
    o4.y = 1.f/(1.f+expf(-c1a));
    o4.z = 1.f/(1.f+expf(-c2a));
    o4.w = sigma;
    *reinterpret_cast<float4*>(out + (size_t)n*4) = o4;
}

extern "C" void kernel_launch(void* const* d_in, const int* in_sizes, int n_in,
                              void* d_out, int out_size, void* d_ws, size_t ws_size,
                              hipStream_t stream) {
    const float* x        = (const float*)d_in[0];
    const float* ht       = (const float*)d_in[1];
    const float* planes   = (const float*)d_in[2];
    const float* embed_a  = (const float*)d_in[3];
    const float* w_sigma0 = (const float*)d_in[4];
    const float* w_sigma1 = (const float*)d_in[5];
    const float* w_color0 = (const float*)d_in[6];
    const float* w_color1 = (const float*)d_in[7];
    const float* w_color2 = (const float*)d_in[8];
    float* out = (float*)d_out;

    int npts = in_sizes[0] / 7;

    // Replicate numpy's RES bit-exactly (same libm chain).
    ResArr res;
    double b = exp((log(2048.0) - log(16.0)) / 15.0);
    for (int l=0; l<NLEV; l++)
        res.v[l] = (float)floor(16.0 * pow(b, (double)l));

    // ws layout: [wT block + app_pre (324352 B)] [feat: npts*16*4 B]
    const size_t F_S0 = 56*64, F_S1 = 64*16, F_C0 = 103*64, F_C1 = 64*64, F_C2 = 64*4;
    const size_t small_floats = F_S0+F_S1+F_C0+F_C1+F_C2 + 1024*64;  // 81088
    const size_t small_bytes  = small_floats*4;                       // 324352
    size_t feat_bytes = (size_t)npts * 16 * sizeof(uint32_t);

    if (ws_size >= small_bytes + feat_bytes) {
        float* f     = (float*)d_ws;
        float* t_s0  = f;
        float* t_s1  = t_s0 + F_S0;
        float* t_c0  = t_s1 + F_S1;
        float* t_c1  = t_c0 + F_C0;
        float* t_c2  = t_c1 + F_C1;
        float* a_pre = t_c2 + F_C2;
        uint32_t* feat = (uint32_t*)((char*)d_ws + small_bytes);

        hipLaunchKernelGGL(nerf_ktrans, dim3(1), dim3(256), 0, stream,
                           w_sigma0, w_sigma1, w_color0, w_color1, w_color2,
                           t_s0, t_s1, t_c0, t_c1, t_c2);
        hipLaunchKernelGGL(nerf_kpre, dim3(1024), dim3(64), 0, stream,
                           embed_a, w_color0, a_pre);

        int chunks = (npts + 511) / 512;
        hipLaunchKernelGGL(nerf_k0, dim3(8*chunks), dim3(256), 0, stream,
                           x, ht, feat, res, npts, 0);
        hipLaunchKernelGGL(nerf_k0, dim3(8*chunks), dim3(256), 0, stream,
                           x, ht, feat, res, npts, 8);

        int g = (npts + 255) / 256;
        hipLaunchKernelGGL(nerf_k1s, dim3(g), dim3(256), 0, stream,
                           x, planes, feat, t_s0, t_s1, npts);
        hipLaunchKernelGGL(nerf_k2s, dim3(g), dim3(256), 0, stream,
                           x, planes, t_c0, t_c1, t_c2, feat, a_pre, out, npts);
    } else {
        int grid = (npts + 255) / 256;
        hipLaunchKernelGGL(nerf_fwd, dim3(grid), dim3(256), 0, stream,
                           x, ht, planes, embed_a,
                           w_sigma0, w_sigma1, w_color0, w_color1, w_color2,
                           out, res, npts);
    }
}